// Round 10
// baseline (801.923 us; speedup 1.0000x reference)
//
#include <hip/hip_runtime.h>
#include <math.h>

#define NN 100000
#define NE 600000
#define NG 64
#define HD 128
#define NL 6
#define NB 1563   // tiles = ceil(NN/64)
#define PSL 16    // pool slices per graph
#define ASTR 136  // LDS A-tile row stride in ushorts (272 B, 16-B aligned)
#define CASTB 12500
#define EBL 2344  // ceil(NE/256)
#define RSTR 379  // rank-remap stride, coprime to NB (neutral-to-positive, kept)
#define GRIDP 782 // gconv blocks: 2 tiles each; 782 <= 1024 residency cap (no deadlock)

typedef unsigned short ushort_t;
typedef short short8 __attribute__((ext_vector_type(8)));
typedef float floatx4 __attribute__((ext_vector_type(4)));

__device__ __forceinline__ float bf2f(ushort_t u) {
    return __uint_as_float(((unsigned)u) << 16);
}
__device__ __forceinline__ ushort_t f2bf(float f) {
    unsigned u = __float_as_uint(f);
    unsigned r = (u + 0x7fffu + ((u >> 16) & 1u)) >> 16;   // round-to-nearest-even
    return (ushort_t)r;
}

// ---------------- prep: x->bf16 cast + W transpose-cast + zero rows + edge hist ----

__global__ __launch_bounds__(256) void k_prep(const float* __restrict__ x,
                                              ushort_t* __restrict__ xb,
                                              const float* __restrict__ W,
                                              ushort_t* __restrict__ Wt,
                                              ushort_t* __restrict__ hb0,
                                              ushort_t* __restrict__ hb1,
                                              const int* __restrict__ ei,
                                              int* __restrict__ counts) {
    int bid = blockIdx.x;
    if (bid < CASTB) {
        int i = bid * 256 + threadIdx.x;   // exactly NN*32 = 12500*256
        float4 v = ((const float4*)x)[i];
        ((ushort4*)xb)[i] = make_ushort4(f2bf(v.x), f2bf(v.y), f2bf(v.z), f2bf(v.w));
    } else if (bid < CASTB + NL) {
        const float* Wl = W + (size_t)(bid - CASTB) * 16384;
        ushort_t* Wtl = Wt + (size_t)(bid - CASTB) * 16384;
        for (int id = threadIdx.x; id < 16384; id += 256) {
            int k = id >> 7, c = id & 127;
            Wtl[c * 128 + k] = f2bf(Wl[id]);
        }
        // zero row NN of xb/hb0/hb1 (dummy target for invalid edge slots)
        if (bid == CASTB && threadIdx.x < 96) {
            int t = threadIdx.x;
            ushort_t* base = (t < 32) ? xb : ((t < 64) ? hb0 : hb1);
            *(ushort4*)(base + (size_t)NN * 128 + (size_t)(t & 31) * 4) =
                make_ushort4(0, 0, 0, 0);
        }
    } else {
        int e = (bid - CASTB - NL) * 256 + threadIdx.x;
        if (e < NE) atomicAdd(&counts[ei[NE + e]], 1);
    }
}

// ---------------- CSR build ----------------

__global__ __launch_bounds__(256) void k_scan1(const int* __restrict__ counts, int* __restrict__ bsums) {
    __shared__ int s[256];
    int i = blockIdx.x * 256 + threadIdx.x;
    s[threadIdx.x] = (i < NN) ? counts[i] : 0;
    __syncthreads();
    for (int off = 128; off > 0; off >>= 1) {
        if (threadIdx.x < off) s[threadIdx.x] += s[threadIdx.x + off];
        __syncthreads();
    }
    if (threadIdx.x == 0) bsums[blockIdx.x] = s[0];
}

// scan3m: per-block inclusive scan of counts + on-the-fly exclusive prefix of bsums
__global__ __launch_bounds__(256) void k_scan3m(const int* __restrict__ counts,
                                                const int* __restrict__ bsums,
                                                int* __restrict__ rowptr) {
    __shared__ int s[256];
    int t = threadIdx.x;
    int i = blockIdx.x * 256 + t;
    int v = (i < NN) ? counts[i] : 0;
    s[t] = v;
    __syncthreads();
    for (int off = 1; off < 256; off <<= 1) {
        int u = (t >= off) ? s[t - off] : 0;
        __syncthreads();
        s[t] += u;
        __syncthreads();
    }
    int incl = s[t];
    // base = sum of bsums[0..blockIdx-1]
    int pb = 0;
    for (int j = t; j < blockIdx.x; j += 256) pb += bsums[j];
    __syncthreads();
    s[t] = pb;
    __syncthreads();
    for (int off = 128; off > 0; off >>= 1) {
        if (t < off) s[t] += s[t + off];
        __syncthreads();
    }
    int base = s[0];
    if (i < NN) rowptr[i] = base + incl - v;
    if (i == 0) rowptr[NN] = NE;
}

// fill + degree-histogram merged (dcount lives at its own ws offset, pre-zeroed)
__global__ __launch_bounds__(256) void k_filldh(const int* __restrict__ ei,
                                                const int* __restrict__ rowptr,
                                                int* __restrict__ cursor,
                                                int* __restrict__ colsrc,
                                                int* __restrict__ dcount,
                                                int ebl) {
    int t = threadIdx.x;
    if ((int)blockIdx.x < ebl) {
        int e = blockIdx.x * 256 + t;
        if (e < NE) {
            int d = ei[NE + e];
            int pos = rowptr[d] + atomicAdd(&cursor[d], 1);
            colsrc[pos] = ei[e];
        }
    } else {
        __shared__ int lc[64];
        if (t < 64) lc[t] = 0;
        __syncthreads();
        int n = (blockIdx.x - ebl) * 256 + t;
        if (n < NN) {
            int d = rowptr[n + 1] - rowptr[n];
            atomicAdd(&lc[min(d, 63)], 1);
        }
        __syncthreads();
        if (t < 64 && lc[t] > 0) atomicAdd(&dcount[t], lc[t]);
    }
}

// dscan + dfill merged: each block derives descending-bucket offsets from dcount
__global__ __launch_bounds__(256) void k_dfill2(const int* __restrict__ rowptr,
                                                const int* __restrict__ dcount,
                                                int* __restrict__ dcursor,
                                                int* __restrict__ perm) {
    __shared__ int lc[64], lbase[64], doffs[64];
    int t = threadIdx.x;
    if (t < 64) {
        lc[t] = 0;
        int s = 0;
        for (int b = t + 1; b < 64; ++b) s += dcount[b];
        doffs[t] = s;
    }
    __syncthreads();
    int n = blockIdx.x * 256 + t;
    int b = 0, my = 0;
    if (n < NN) {
        int d = rowptr[n + 1] - rowptr[n];
        b = min(d, 63);
        my = atomicAdd(&lc[b], 1);
    }
    __syncthreads();
    if (t < 64 && lc[t] > 0) lbase[t] = atomicAdd(&dcursor[t], lc[t]);
    __syncthreads();
    if (n < NN) perm[doffs[b] + lbase[b] + my] = n;
}

// ---------------- Fused layer ----------------
// R10: R7's verified gconv (68 us, 73.6 MB) with the k_red fold. Blocks 0-63
// reduce the PREVIOUS layer's partials into stats at kernel start (~3 us),
// then signal done_flag (device-scope). All blocks wait for done==64 lazily --
// just before the FIRST pack step, which sits ~10+ us of gather work into the
// kernel, so the wait is normally already satisfied. Deadlock-free without
// cooperative launch: grid = 782 <= 1024 residency capacity (launch_bounds
// (256,4), 18.4 KB LDS) and reducers never wait. Partials double-buffered by
// layer parity. 2 tiles per block via grid-stride; stats accumulate across
// both tiles in sstat as before.

__global__ __launch_bounds__(256, 4) void k_gconv(
    const ushort_t* __restrict__ hin, const int* __restrict__ perm,
    const int* __restrict__ rowptr, const int* __restrict__ colsrc,
    const float* __restrict__ red_src,   // prev-layer partials (nullptr for L=0)
    float* __restrict__ stats_prev,      // stats+(L-1)*256 (nullptr for L=0)
    int* __restrict__ done_flag,         // done+(L-1)      (nullptr for L=0)
    const float* __restrict__ bng, const float* __restrict__ bnb,
    const ushort_t* __restrict__ Wt, const float* __restrict__ bias,
    ushort_t* __restrict__ hout, float* __restrict__ partials_out) {
    __shared__ ushort_t Ab[64 * ASTR];   // 17408 B
    __shared__ float sstat[256];
    int t = threadIdx.x;
    sstat[t] = 0.f;
    __syncthreads();   // sstat zero visible to all waves
    int wave = t >> 6, lane = t & 63;
    int l15 = lane & 15, quad = lane >> 4;
    int l5 = lane & 31, half = lane >> 5;
    int f0 = l5 * 4;

    // Folded k_red: blocks 0-63 reduce previous layer's partials -> stats_prev
    if (red_src != nullptr && blockIdx.x < 64) {
        float s = 0.f;
        for (int r = blockIdx.x; r < GRIDP; r += 64)
            s += red_src[(size_t)r * 256 + t];
        atomicAdd(&stats_prev[t], s);
        __threadfence();
        __syncthreads();   // all 256 atomics of this block performed
        if (t == 0)
            __hip_atomic_fetch_add(done_flag, 1, __ATOMIC_RELEASE,
                                   __HIP_MEMORY_SCOPE_AGENT);
    }

    bool have_stats = (done_flag == nullptr);   // layer 0 needs no stats
    float sc[4] = {1.f, 1.f, 1.f, 1.f}, sh[4] = {0.f, 0.f, 0.f, 0.f};

    const uint2* hbl = (const uint2*)hin + l5;   // lane's 8-B column in any row

    for (int tile = blockIdx.x; tile < NB; tile += GRIDP) {
        int rank = (RSTR * tile) % NB;
        int rowbase = rank * 64 + wave * 16;

        // wave-hoisted row metadata (lanes replicate mod 16)
        int idxg = rowbase + l15;
        bool vr = idxg < NN;
        int prm = vr ? perm[idxg] : 0;
        int rb = vr ? rowptr[prm] : 0;
        int re = vr ? rowptr[prm + 1] : 0;
        int dg = re - rb;

        // pipeline prologue: b/d + first colsrc batch for group 0
        int b0 = __shfl(rb, half, 64);
        int d0 = __shfl(dg, half, 64);
        int b1 = __shfl(rb, 2 + half, 64);
        int d1 = __shfl(dg, 2 + half, 64);
        int cs0[4], cs1[4];
        #pragma unroll
        for (int eo = 0; eo < 4; ++eo) {
            int c0 = colsrc[b0 + eo];
            int c1 = colsrc[b1 + eo];
            cs0[eo] = (eo < d0) ? c0 : NN;
            cs1[eo] = (eo < d1) ? c1 : NN;
        }

        #pragma unroll 1
        for (int g = 0; g < 4; ++g) {
            int mx = max(d0, d1);
            mx = max(mx, __shfl_xor(mx, 32, 64));   // wave-uniform group max degree

            float a0[4] = {0.f, 0.f, 0.f, 0.f};
            float a1[4] = {0.f, 0.f, 0.f, 0.f};

            #pragma unroll 1
            for (int e = 0; e < mx; e += 4) {
                uint2 hv0[4], hv1[4];
                #pragma unroll
                for (int eo = 0; eo < 4; ++eo) hv0[eo] = hbl[(size_t)cs0[eo] * 32];
                #pragma unroll
                for (int eo = 0; eo < 4; ++eo) hv1[eo] = hbl[(size_t)cs1[eo] * 32];
                int nc0[4], nc1[4];
                #pragma unroll
                for (int eo = 0; eo < 4; ++eo) {
                    int e4 = e + 4 + eo;
                    int c0 = colsrc[b0 + e4];
                    int c1 = colsrc[b1 + e4];
                    nc0[eo] = (e4 < d0) ? c0 : NN;
                    nc1[eo] = (e4 < d1) ? c1 : NN;
                }
                #pragma unroll
                for (int eo = 0; eo < 4; ++eo) {
                    unsigned wx = hv0[eo].x, wy = hv0[eo].y;
                    a0[0] += __uint_as_float(wx << 16);
                    a0[1] += __uint_as_float(wx & 0xffff0000u);
                    a0[2] += __uint_as_float(wy << 16);
                    a0[3] += __uint_as_float(wy & 0xffff0000u);
                    unsigned zx = hv1[eo].x, zy = hv1[eo].y;
                    a1[0] += __uint_as_float(zx << 16);
                    a1[1] += __uint_as_float(zx & 0xffff0000u);
                    a1[2] += __uint_as_float(zy << 16);
                    a1[3] += __uint_as_float(zy & 0xffff0000u);
                }
                #pragma unroll
                for (int eo = 0; eo < 4; ++eo) { cs0[eo] = nc0[eo]; cs1[eo] = nc1[eo]; }
            }

            // prefetch next group's colsrc under this group's epilogue VALU
            int nb0 = 0, nd0 = 0, nb1 = 0, nd1 = 0;
            if (g < 3) {
                int t0 = (g + 1) * 4 + half, t1 = t0 + 2;
                nb0 = __shfl(rb, t0, 64);
                nd0 = __shfl(dg, t0, 64);
                nb1 = __shfl(rb, t1, 64);
                nd1 = __shfl(dg, t1, 64);
                #pragma unroll
                for (int eo = 0; eo < 4; ++eo) {
                    int c0 = colsrc[nb0 + eo];
                    int c1 = colsrc[nb1 + eo];
                    cs0[eo] = (eo < nd0) ? c0 : NN;
                    cs1[eo] = (eo < nd1) ? c1 : NN;
                }
            }

            // Lazy BN-constant acquisition: wait for folded reduction (first pack
            // only). Uniform branch; flag is normally set long before we get here.
            if (!have_stats) {
                if (t == 0) {
                    while (__hip_atomic_load(done_flag, __ATOMIC_ACQUIRE,
                                             __HIP_MEMORY_SCOPE_AGENT) < 64)
                        __builtin_amdgcn_s_sleep(8);
                }
                __syncthreads();
                const float inv_n = 1.0f / (float)NN;
                #pragma unroll
                for (int j = 0; j < 4; ++j) {
                    float s1 = __hip_atomic_load(&stats_prev[f0 + j], __ATOMIC_RELAXED,
                                                 __HIP_MEMORY_SCOPE_AGENT);
                    float s2 = __hip_atomic_load(&stats_prev[HD + f0 + j], __ATOMIC_RELAXED,
                                                 __HIP_MEMORY_SCOPE_AGENT);
                    float m = s1 * inv_n;
                    float var = fmaf(-m, m, s2 * inv_n);
                    sc[j] = bng[f0 + j] * rsqrtf(var + 1e-5f);
                    sh[j] = bnb[f0 + j] - m * sc[j];
                }
                have_stats = true;
            }

            // BN affine + pack to LDS (rows g*4+half and g*4+2+half of wave slice)
            float df0 = (float)d0, df1 = (float)d1;
            ushort4 u0, u1;
            u0.x = f2bf(fmaf(sc[0], a0[0], df0 * sh[0]));
            u0.y = f2bf(fmaf(sc[1], a0[1], df0 * sh[1]));
            u0.z = f2bf(fmaf(sc[2], a0[2], df0 * sh[2]));
            u0.w = f2bf(fmaf(sc[3], a0[3], df0 * sh[3]));
            u1.x = f2bf(fmaf(sc[0], a1[0], df1 * sh[0]));
            u1.y = f2bf(fmaf(sc[1], a1[1], df1 * sh[1]));
            u1.z = f2bf(fmaf(sc[2], a1[2], df1 * sh[2]));
            u1.w = f2bf(fmaf(sc[3], a1[3], df1 * sh[3]));
            *(ushort4*)&Ab[(wave * 16 + g * 4 + half) * ASTR + f0] = u0;
            *(ushort4*)&Ab[(wave * 16 + g * 4 + 2 + half) * ASTR + f0] = u1;

            b0 = nb0; d0 = nd0; b1 = nb1; d1 = nd1;
        }
        // NO mid barrier: Ab slice is wave-private; per-wave LDS ordering holds.

        // A-fragments from LDS: A[m=l15][k=quad*8+j + s*32]
        short8 afrag[4];
        #pragma unroll
        for (int s = 0; s < 4; ++s)
            afrag[s] = *(const short8*)&Ab[(wave * 16 + l15) * ASTR + quad * 8 + s * 32];

        // MFMA phase (verified path)
        floatx4 acc[8];
        #pragma unroll
        for (int c = 0; c < 8; ++c) acc[c] = (floatx4){0.f, 0.f, 0.f, 0.f};
        #pragma unroll
        for (int c = 0; c < 8; ++c) {
            size_t boff = (size_t)(16 * c + l15) * 128 + quad * 8;
            #pragma unroll
            for (int s = 0; s < 4; ++s) {
                short8 bf = *(const short8*)(Wt + boff + 32 * s);
                acc[c] = __builtin_amdgcn_mfma_f32_16x16x32_bf16(afrag[s], bf, acc[c], 0, 0, 0);
            }
        }

        // Epilogue: bias+relu+round, stats, write D back into own LDS slice.
        int orow0 = rowbase + quad * 4;
        #pragma unroll
        for (int c = 0; c < 8; ++c) {
            int col = 16 * c + l15;
            float bv = bias[col];
            float ls = 0.f, lq = 0.f;
            #pragma unroll
            for (int i = 0; i < 4; ++i) {
                float v = fmaxf(acc[c][i] + bv, 0.f);
                ushort_t bb = f2bf(v);
                Ab[(wave * 16 + quad * 4 + i) * ASTR + col] = bb;
                if (orow0 + i < NN) {
                    float vr2 = bf2f(bb);
                    ls += vr2;
                    lq = fmaf(vr2, vr2, lq);
                }
            }
            ls += __shfl_xor(ls, 16, 64);
            ls += __shfl_xor(ls, 32, 64);
            lq += __shfl_xor(lq, 16, 64);
            lq += __shfl_xor(lq, 32, 64);
            if (quad == 0) {
                atomicAdd(&sstat[col], ls);
                atomicAdd(&sstat[128 + col], lq);
            }
        }

        // Full-line stores: per iteration, each quad stores one FULL 256-B row.
        #pragma unroll
        for (int it = 0; it < 4; ++it) {
            int pr = __shfl(prm, it * 4 + quad, 64);
            int ridx = rowbase + it * 4 + quad;
            if (ridx < NN) {
                short8 v = *(const short8*)&Ab[(wave * 16 + it * 4 + quad) * ASTR + l15 * 8];
                *(short8*)(hout + (size_t)pr * 128 + l15 * 8) = v;
            }
        }
    }

    __syncthreads();   // all waves' sstat atomics (both tiles) complete
    partials_out[(size_t)blockIdx.x * 256 + t] = sstat[t];   // coalesced 1 KB store
}

// ---------------- Pooling, phase 1 (+ folded layer-5 stats reduction) ---------

__device__ __forceinline__ int lowerb(const int* __restrict__ b, int n, int key) {
    int lo = 0, hi = n;
    while (lo < hi) {
        int mid = (lo + hi) >> 1;
        if (b[mid] < key) lo = mid + 1;
        else hi = mid;
    }
    return lo;
}

__global__ __launch_bounds__(256) void k_pool1(
    const ushort_t* __restrict__ h, const int* __restrict__ batch,
    float* __restrict__ ppart,
    const float* __restrict__ red_src, float* __restrict__ stats5) {
    int t = threadIdx.x;
    // folded k_red for layer 5 (consumed by k_tail, next dispatch -- stream order)
    if (blockIdx.x < 64) {
        float s = 0.f;
        for (int r = blockIdx.x; r < GRIDP; r += 64)
            s += red_src[(size_t)r * 256 + t];
        atomicAdd(&stats5[t], s);
    }
    int g = blockIdx.x >> 4;
    int sl = blockIdx.x & (PSL - 1);
    int lo = lowerb(batch, NN, g);
    int hi = lowerb(batch, NN, g + 1);
    int cnt = hi - lo;
    int a = lo + (int)(((long long)cnt * sl) >> 4);
    int b = lo + (int)(((long long)cnt * (sl + 1)) >> 4);
    int wave = t >> 6, lane = t & 63;
    const ushort2* h2 = (const ushort2*)h;
    float ax = 0.f, ay = 0.f;
    for (int n = a + wave; n < b; n += 4) {
        ushort2 v = h2[(size_t)n * 64 + lane];
        ax += bf2f(v.x);
        ay += bf2f(v.y);
    }
    __shared__ float2 red[4][64];
    red[wave][lane] = make_float2(ax, ay);
    __syncthreads();
    if (wave == 0) {
        float sx = 0.f, sy = 0.f;
        for (int w = 0; w < 4; ++w) {
            sx += red[w][lane].x;
            sy += red[w][lane].y;
        }
        ((float2*)ppart)[(size_t)blockIdx.x * 64 + lane] = make_float2(sx, sy);
    }
}

// ---------------- Tail: combine slices + deferred BN affine + MLP head + log_softmax

__global__ __launch_bounds__(64) void k_tail(
    const float* __restrict__ ppart, const int* __restrict__ batch,
    const float* __restrict__ stats, const float* __restrict__ bng, const float* __restrict__ bnb,
    const float* __restrict__ w1, const float* __restrict__ b1,
    const float* __restrict__ w2, const float* __restrict__ b2,
    float* __restrict__ out) {
    __shared__ float p[128];
    int g = blockIdx.x;
    int lane = threadIdx.x;
    float sx = 0.f, sy = 0.f;
    #pragma unroll
    for (int s = 0; s < PSL; ++s) {
        float2 v = ((const float2*)ppart)[(size_t)(g * PSL + s) * 64 + lane];
        sx += v.x;
        sy += v.y;
    }
    int cnt = lowerb(batch, NN, g + 1) - lowerb(batch, NN, g);
    int c0 = lane * 2;
    const float inv_n = 1.0f / (float)NN;
    float m0 = stats[c0] * inv_n, m1 = stats[c0 + 1] * inv_n;
    float var0 = fmaf(-m0, m0, stats[HD + c0] * inv_n);
    float var1 = fmaf(-m1, m1, stats[HD + c0 + 1] * inv_n);
    float sc0 = bng[c0] * rsqrtf(var0 + 1e-5f);
    float sc1 = bng[c0 + 1] * rsqrtf(var1 + 1e-5f);
    float sh0 = bnb[c0] - m0 * sc0;
    float sh1 = bnb[c0 + 1] - m1 * sc1;
    float denom = fmaxf((float)cnt, 1.f);
    p[c0] = (sc0 * sx + (float)cnt * sh0) / denom;
    p[c0 + 1] = (sc1 * sy + (float)cnt * sh1) / denom;
    __syncthreads();

    float hid = b1[lane];
    #pragma unroll 8
    for (int k = 0; k < 128; ++k) hid = fmaf(p[k], w1[k * 64 + lane], hid);
    float o[4];
    #pragma unroll
    for (int c = 0; c < 4; ++c) {
        float v = hid * w2[lane * 4 + c];
        #pragma unroll
        for (int off = 1; off < 64; off <<= 1) v += __shfl_xor(v, off, 64);
        o[c] = v + b2[c];
    }
    if (lane == 0) {
        float mx = fmaxf(fmaxf(o[0], o[1]), fmaxf(o[2], o[3]));
        float se = expf(o[0] - mx) + expf(o[1] - mx) + expf(o[2] - mx) + expf(o[3] - mx);
        float ls = mx + logf(se);
        #pragma unroll
        for (int c = 0; c < 4; ++c) out[g * 4 + c] = o[c] - ls;
    }
}

extern "C" void kernel_launch(void* const* d_in, const int* in_sizes, int n_in,
                              void* d_out, int out_size, void* d_ws, size_t ws_size,
                              hipStream_t stream) {
    const float* x = (const float*)d_in[0];
    const int* ei = (const int*)d_in[1];
    const int* batch = (const int*)d_in[2];
    const float* conv_w = (const float*)d_in[3];
    const float* conv_b = (const float*)d_in[4];
    const float* bn_g = (const float*)d_in[5];
    const float* bn_b = (const float*)d_in[6];
    const float* l1w = (const float*)d_in[7];
    const float* l1b = (const float*)d_in[8];
    const float* l2w = (const float*)d_in[9];
    const float* l2b = (const float*)d_in[10];
    float* out = (float*)d_out;
    (void)in_sizes; (void)n_in; (void)out_size; (void)ws_size;

    char* ws = (char*)d_ws;
    int* counts = (int*)(ws + 0);               // 400000 B
    int* cursor = (int*)(ws + 400000);          // 400000 B
    int* perm = (int*)(ws + 400000);            // reuse after k_filldh
    float* stats = (float*)(ws + 800000);       // 6*256 floats -> 806144
    int* dcount = (int*)(ws + 806144);          // 256 B
    int* dcursor = (int*)(ws + 806400);         // 256 B -> 806656
    int* done = (int*)(ws + 806656);            // 5 ints + pad -> 806912
    const size_t zero_bytes = 806912;           // counts+cursor+stats+dcount+dcursor+done
    int* rowptr = (int*)(ws + 806912);          // 100001 ints -> 1206916
    int* bsums = (int*)(ws + 1206920);          // 391 ints -> 1208484
    int* colsrc = (int*)(ws + 1208512);         // 600000 ints + 1 KiB pad -> 3609536
    float* ppart = (float*)(ws + 3609536);      // 1024*128 floats -> 4133824
    float* partials0 = (float*)(ws + 4133824);  // 782*256 floats -> 4934592
    float* partials1 = (float*)(ws + 4934592);  // 782*256 floats -> 5735360
    ushort_t* xb = (ushort_t*)(ws + 5735424);   // 25600256 B -> 31335680
    ushort_t* hb0 = (ushort_t*)(ws + 31335680); // 25600256 B -> 56935936
    ushort_t* hb1 = (ushort_t*)(ws + 56935936); // 25600256 B -> 82536192
    ushort_t* wtbuf = (ushort_t*)(ws + 82536192); // 196608 B -> 82732800

    hipMemsetAsync(ws, 0, zero_bytes, stream);

    // cast + wcast + zero rows + edge histogram in one grid
    k_prep<<<CASTB + NL + EBL, 256, 0, stream>>>(x, xb, conv_w, wtbuf, hb0, hb1, ei, counts);

    int nb1 = (NN + 255) / 256;   // 391
    k_scan1<<<nb1, 256, 0, stream>>>(counts, bsums);
    k_scan3m<<<nb1, 256, 0, stream>>>(counts, bsums, rowptr);
    k_filldh<<<EBL + nb1, 256, 0, stream>>>(ei, rowptr, cursor, colsrc, dcount, EBL);
    k_dfill2<<<nb1, 256, 0, stream>>>(rowptr, dcount, dcursor, perm);

    // ping-pong h buffers; k_red folded into the NEXT layer's gconv (blocks 0-63)
    ushort_t* hb[2] = {hb0, hb1};
    float* parts[2] = {partials0, partials1};
    for (int L = 0; L < NL; ++L) {
        const ushort_t* hin = (L == 0) ? xb : hb[(L + 1) & 1];
        ushort_t* hout = hb[L & 1];
        const float* red_src = (L == 0) ? nullptr : parts[(L - 1) & 1];
        float* stats_prev = (L == 0) ? nullptr : (stats + (L - 1) * 256);
        int* done_flag = (L == 0) ? nullptr : (done + (L - 1));
        const float* lg = (L == 0) ? nullptr : (bn_g + (L - 1) * 128);
        const float* lb = (L == 0) ? nullptr : (bn_b + (L - 1) * 128);
        k_gconv<<<GRIDP, 256, 0, stream>>>(hin, perm, rowptr, colsrc,
                                           red_src, stats_prev, done_flag, lg, lb,
                                           wtbuf + L * 16384, conv_b + L * 128,
                                           hout, parts[L & 1]);
    }
    // final h is hb[5&1] = hb1; layer-5 stats reduction folded into pool1
    k_pool1<<<NG * PSL, 256, 0, stream>>>(hb1, batch, ppart, parts[(NL - 1) & 1],
                                          stats + 5 * 256);
    k_tail<<<NG, 64, 0, stream>>>(ppart, batch, stats + 5 * 256, bn_g + 5 * 128, bn_b + 5 * 128,
                                  l1w, l1b, l2w, l2b, out);
}

// Round 11
// 638.221 us; speedup vs baseline: 1.2565x; 1.2565x over previous
//
#include <hip/hip_runtime.h>
#include <math.h>

#define NN 100000
#define NE 600000
#define NG 64
#define HD 128
#define NL 6
#define NB 1563   // gconv blocks = ceil(NN/64)
#define PSL 16    // pool slices per graph
#define ASTR 136  // LDS A-tile row stride in ushorts (272 B, 16-B aligned)
#define CASTB 12500
#define EBL 2344  // ceil(NE/256)
#define RSTR 379  // rank-remap stride, coprime to NB (neutral-to-positive, kept)

typedef unsigned short ushort_t;
typedef short short8 __attribute__((ext_vector_type(8)));
typedef float floatx4 __attribute__((ext_vector_type(4)));

__device__ __forceinline__ float bf2f(ushort_t u) {
    return __uint_as_float(((unsigned)u) << 16);
}
__device__ __forceinline__ ushort_t f2bf(float f) {
    unsigned u = __float_as_uint(f);
    unsigned r = (u + 0x7fffu + ((u >> 16) & 1u)) >> 16;   // round-to-nearest-even
    return (ushort_t)r;
}

// ---------------- prep: x->bf16 cast + W transpose-cast + zero rows + edge hist ----

__global__ __launch_bounds__(256) void k_prep(const float* __restrict__ x,
                                              ushort_t* __restrict__ xb,
                                              const float* __restrict__ W,
                                              ushort_t* __restrict__ Wt,
                                              ushort_t* __restrict__ hb0,
                                              ushort_t* __restrict__ hb1,
                                              const int* __restrict__ ei,
                                              int* __restrict__ counts) {
    int bid = blockIdx.x;
    if (bid < CASTB) {
        int i = bid * 256 + threadIdx.x;   // exactly NN*32 = 12500*256
        float4 v = ((const float4*)x)[i];
        ((ushort4*)xb)[i] = make_ushort4(f2bf(v.x), f2bf(v.y), f2bf(v.z), f2bf(v.w));
    } else if (bid < CASTB + NL) {
        const float* Wl = W + (size_t)(bid - CASTB) * 16384;
        ushort_t* Wtl = Wt + (size_t)(bid - CASTB) * 16384;
        for (int id = threadIdx.x; id < 16384; id += 256) {
            int k = id >> 7, c = id & 127;
            Wtl[c * 128 + k] = f2bf(Wl[id]);
        }
        // zero row NN of xb/hb0/hb1 (dummy target for invalid edge slots)
        if (bid == CASTB && threadIdx.x < 96) {
            int t = threadIdx.x;
            ushort_t* base = (t < 32) ? xb : ((t < 64) ? hb0 : hb1);
            *(ushort4*)(base + (size_t)NN * 128 + (size_t)(t & 31) * 4) =
                make_ushort4(0, 0, 0, 0);
        }
    } else {
        int e = (bid - CASTB - NL) * 256 + threadIdx.x;
        if (e < NE) atomicAdd(&counts[ei[NE + e]], 1);
    }
}

// ---------------- CSR build ----------------

__global__ __launch_bounds__(256) void k_scan1(const int* __restrict__ counts, int* __restrict__ bsums) {
    __shared__ int s[256];
    int i = blockIdx.x * 256 + threadIdx.x;
    s[threadIdx.x] = (i < NN) ? counts[i] : 0;
    __syncthreads();
    for (int off = 128; off > 0; off >>= 1) {
        if (threadIdx.x < off) s[threadIdx.x] += s[threadIdx.x + off];
        __syncthreads();
    }
    if (threadIdx.x == 0) bsums[blockIdx.x] = s[0];
}

// scan3m: per-block inclusive scan of counts + on-the-fly exclusive prefix of bsums
__global__ __launch_bounds__(256) void k_scan3m(const int* __restrict__ counts,
                                                const int* __restrict__ bsums,
                                                int* __restrict__ rowptr) {
    __shared__ int s[256];
    int t = threadIdx.x;
    int i = blockIdx.x * 256 + t;
    int v = (i < NN) ? counts[i] : 0;
    s[t] = v;
    __syncthreads();
    for (int off = 1; off < 256; off <<= 1) {
        int u = (t >= off) ? s[t - off] : 0;
        __syncthreads();
        s[t] += u;
        __syncthreads();
    }
    int incl = s[t];
    // base = sum of bsums[0..blockIdx-1]
    int pb = 0;
    for (int j = t; j < blockIdx.x; j += 256) pb += bsums[j];
    __syncthreads();
    s[t] = pb;
    __syncthreads();
    for (int off = 128; off > 0; off >>= 1) {
        if (t < off) s[t] += s[t + off];
        __syncthreads();
    }
    int base = s[0];
    if (i < NN) rowptr[i] = base + incl - v;
    if (i == 0) rowptr[NN] = NE;
}

// fill + degree-histogram merged (dcount lives at its own ws offset, pre-zeroed)
__global__ __launch_bounds__(256) void k_filldh(const int* __restrict__ ei,
                                                const int* __restrict__ rowptr,
                                                int* __restrict__ cursor,
                                                int* __restrict__ colsrc,
                                                int* __restrict__ dcount,
                                                int ebl) {
    int t = threadIdx.x;
    if ((int)blockIdx.x < ebl) {
        int e = blockIdx.x * 256 + t;
        if (e < NE) {
            int d = ei[NE + e];
            int pos = rowptr[d] + atomicAdd(&cursor[d], 1);
            colsrc[pos] = ei[e];
        }
    } else {
        __shared__ int lc[64];
        if (t < 64) lc[t] = 0;
        __syncthreads();
        int n = (blockIdx.x - ebl) * 256 + t;
        if (n < NN) {
            int d = rowptr[n + 1] - rowptr[n];
            atomicAdd(&lc[min(d, 63)], 1);
        }
        __syncthreads();
        if (t < 64 && lc[t] > 0) atomicAdd(&dcount[t], lc[t]);
    }
}

// dscan + dfill merged: each block derives descending-bucket offsets from dcount
__global__ __launch_bounds__(256) void k_dfill2(const int* __restrict__ rowptr,
                                                const int* __restrict__ dcount,
                                                int* __restrict__ dcursor,
                                                int* __restrict__ perm) {
    __shared__ int lc[64], lbase[64], doffs[64];
    int t = threadIdx.x;
    if (t < 64) {
        lc[t] = 0;
        int s = 0;
        for (int b = t + 1; b < 64; ++b) s += dcount[b];
        doffs[t] = s;
    }
    __syncthreads();
    int n = blockIdx.x * 256 + t;
    int b = 0, my = 0;
    if (n < NN) {
        int d = rowptr[n + 1] - rowptr[n];
        b = min(d, 63);
        my = atomicAdd(&lc[b], 1);
    }
    __syncthreads();
    if (t < 64 && lc[t] > 0) lbase[t] = atomicAdd(&dcursor[t], lc[t]);
    __syncthreads();
    if (n < NN) perm[doffs[b] + lbase[b] + my] = n;
}

// ---------------- Fused layer ----------------
// R11: k_gconv reverted byte-for-byte to R7 (best measured: 68 us, 73.6 MB FETCH,
// VGPR 52). R10's spin-fold caused ~80 MB of symmetric scratch-spill traffic and
// +35 us/dispatch -- cross-dispatch folding into gconv is a dead end on this
// harness (as is cooperative launch, R9). Only the layer-5 k_red fold into pool1
// survives (stream-ordered before k_tail, verified in R10's passing run).

__global__ __launch_bounds__(256, 4) void k_gconv(
    const ushort_t* __restrict__ hin, const int* __restrict__ perm,
    const int* __restrict__ rowptr, const int* __restrict__ colsrc,
    const float* __restrict__ stats_in, const float* __restrict__ bng,
    const float* __restrict__ bnb,
    const ushort_t* __restrict__ Wt, const float* __restrict__ bias,
    ushort_t* __restrict__ hout, float* __restrict__ partials) {
    __shared__ ushort_t Ab[64 * ASTR];   // 17408 B
    __shared__ float sstat[256];
    int t = threadIdx.x;
    sstat[t] = 0.f;
    __syncthreads();   // sstat zero visible to all waves (only cross-wave LDS dep)
    int wave = t >> 6, lane = t & 63;
    int l15 = lane & 15, quad = lane >> 4;
    int l5 = lane & 31, half = lane >> 5;
    int rank = (RSTR * blockIdx.x) % NB;
    int rowbase = rank * 64 + wave * 16;

    // wave-hoisted row metadata (lanes replicate mod 16) -- contiguous sorted rows
    int idxg = rowbase + l15;
    bool vr = idxg < NN;
    int prm = vr ? perm[idxg] : 0;
    int rb = vr ? rowptr[prm] : 0;
    int re = vr ? rowptr[prm + 1] : 0;
    int dg = re - rb;

    // deferred BN affine for this lane's 4 features f0..f0+3 (f32 stats)
    int f0 = l5 * 4;
    float sc[4] = {1.f, 1.f, 1.f, 1.f}, sh[4] = {0.f, 0.f, 0.f, 0.f};
    if (stats_in != nullptr) {
        const float inv_n = 1.0f / (float)NN;
        float4 s1 = *(const float4*)&stats_in[f0];
        float4 s2 = *(const float4*)&stats_in[HD + f0];
        float4 g4 = *(const float4*)&bng[f0];
        float4 b4 = *(const float4*)&bnb[f0];
        float m, var;
        m = s1.x * inv_n; var = fmaf(-m, m, s2.x * inv_n);
        sc[0] = g4.x * rsqrtf(var + 1e-5f); sh[0] = b4.x - m * sc[0];
        m = s1.y * inv_n; var = fmaf(-m, m, s2.y * inv_n);
        sc[1] = g4.y * rsqrtf(var + 1e-5f); sh[1] = b4.y - m * sc[1];
        m = s1.z * inv_n; var = fmaf(-m, m, s2.z * inv_n);
        sc[2] = g4.z * rsqrtf(var + 1e-5f); sh[2] = b4.z - m * sc[2];
        m = s1.w * inv_n; var = fmaf(-m, m, s2.w * inv_n);
        sc[3] = g4.w * rsqrtf(var + 1e-5f); sh[3] = b4.w - m * sc[3];
    }

    const uint2* hbl = (const uint2*)hin + l5;   // lane's 8-B column within any row

    // pipeline prologue: b/d + first colsrc batch for group 0
    int b0 = __shfl(rb, half, 64);
    int d0 = __shfl(dg, half, 64);
    int b1 = __shfl(rb, 2 + half, 64);
    int d1 = __shfl(dg, 2 + half, 64);
    int cs0[4], cs1[4];
    #pragma unroll
    for (int eo = 0; eo < 4; ++eo) {
        int c0 = colsrc[b0 + eo];
        int c1 = colsrc[b1 + eo];
        cs0[eo] = (eo < d0) ? c0 : NN;
        cs1[eo] = (eo < d1) ? c1 : NN;
    }

    #pragma unroll 1
    for (int g = 0; g < 4; ++g) {
        int mx = max(d0, d1);
        mx = max(mx, __shfl_xor(mx, 32, 64));   // wave-uniform group max degree

        float a0[4] = {0.f, 0.f, 0.f, 0.f};
        float a1[4] = {0.f, 0.f, 0.f, 0.f};

        #pragma unroll 1
        for (int e = 0; e < mx; e += 4) {
            uint2 hv0[4], hv1[4];
            #pragma unroll
            for (int eo = 0; eo < 4; ++eo) hv0[eo] = hbl[(size_t)cs0[eo] * 32];
            #pragma unroll
            for (int eo = 0; eo < 4; ++eo) hv1[eo] = hbl[(size_t)cs1[eo] * 32];
            int nc0[4], nc1[4];
            #pragma unroll
            for (int eo = 0; eo < 4; ++eo) {
                int e4 = e + 4 + eo;
                int c0 = colsrc[b0 + e4];
                int c1 = colsrc[b1 + e4];
                nc0[eo] = (e4 < d0) ? c0 : NN;
                nc1[eo] = (e4 < d1) ? c1 : NN;
            }
            #pragma unroll
            for (int eo = 0; eo < 4; ++eo) {
                unsigned wx = hv0[eo].x, wy = hv0[eo].y;
                a0[0] += __uint_as_float(wx << 16);
                a0[1] += __uint_as_float(wx & 0xffff0000u);
                a0[2] += __uint_as_float(wy << 16);
                a0[3] += __uint_as_float(wy & 0xffff0000u);
                unsigned zx = hv1[eo].x, zy = hv1[eo].y;
                a1[0] += __uint_as_float(zx << 16);
                a1[1] += __uint_as_float(zx & 0xffff0000u);
                a1[2] += __uint_as_float(zy << 16);
                a1[3] += __uint_as_float(zy & 0xffff0000u);
            }
            #pragma unroll
            for (int eo = 0; eo < 4; ++eo) { cs0[eo] = nc0[eo]; cs1[eo] = nc1[eo]; }
        }

        // prefetch next group's colsrc under this group's epilogue VALU
        int nb0 = 0, nd0 = 0, nb1 = 0, nd1 = 0;
        if (g < 3) {
            int t0 = (g + 1) * 4 + half, t1 = t0 + 2;
            nb0 = __shfl(rb, t0, 64);
            nd0 = __shfl(dg, t0, 64);
            nb1 = __shfl(rb, t1, 64);
            nd1 = __shfl(dg, t1, 64);
            #pragma unroll
            for (int eo = 0; eo < 4; ++eo) {
                int c0 = colsrc[nb0 + eo];
                int c1 = colsrc[nb1 + eo];
                cs0[eo] = (eo < nd0) ? c0 : NN;
                cs1[eo] = (eo < nd1) ? c1 : NN;
            }
        }

        // BN affine + pack to LDS (rows g*4+half and g*4+2+half of this wave's slice)
        float df0 = (float)d0, df1 = (float)d1;
        ushort4 u0, u1;
        u0.x = f2bf(fmaf(sc[0], a0[0], df0 * sh[0]));
        u0.y = f2bf(fmaf(sc[1], a0[1], df0 * sh[1]));
        u0.z = f2bf(fmaf(sc[2], a0[2], df0 * sh[2]));
        u0.w = f2bf(fmaf(sc[3], a0[3], df0 * sh[3]));
        u1.x = f2bf(fmaf(sc[0], a1[0], df1 * sh[0]));
        u1.y = f2bf(fmaf(sc[1], a1[1], df1 * sh[1]));
        u1.z = f2bf(fmaf(sc[2], a1[2], df1 * sh[2]));
        u1.w = f2bf(fmaf(sc[3], a1[3], df1 * sh[3]));
        *(ushort4*)&Ab[(wave * 16 + g * 4 + half) * ASTR + f0] = u0;
        *(ushort4*)&Ab[(wave * 16 + g * 4 + 2 + half) * ASTR + f0] = u1;

        b0 = nb0; d0 = nd0; b1 = nb1; d1 = nd1;
    }
    // NO mid-kernel barrier: Ab slice is wave-private; per-wave LDS ordering
    // guarantees the writes above precede the reads below.

    // A-fragments from LDS: A[m=l15][k=quad*8+j + s*32]
    short8 afrag[4];
    #pragma unroll
    for (int s = 0; s < 4; ++s)
        afrag[s] = *(const short8*)&Ab[(wave * 16 + l15) * ASTR + quad * 8 + s * 32];

    // MFMA phase (verified path)
    floatx4 acc[8];
    #pragma unroll
    for (int c = 0; c < 8; ++c) acc[c] = (floatx4){0.f, 0.f, 0.f, 0.f};
    #pragma unroll
    for (int c = 0; c < 8; ++c) {
        size_t boff = (size_t)(16 * c + l15) * 128 + quad * 8;
        #pragma unroll
        for (int s = 0; s < 4; ++s) {
            short8 bf = *(const short8*)(Wt + boff + 32 * s);
            acc[c] = __builtin_amdgcn_mfma_f32_16x16x32_bf16(afrag[s], bf, acc[c], 0, 0, 0);
        }
    }

    // Epilogue: bias+relu+round, stats, write D back into own LDS slice.
    int orow0 = rowbase + quad * 4;
    #pragma unroll
    for (int c = 0; c < 8; ++c) {
        int col = 16 * c + l15;
        float bv = bias[col];
        float ls = 0.f, lq = 0.f;
        #pragma unroll
        for (int i = 0; i < 4; ++i) {
            float v = fmaxf(acc[c][i] + bv, 0.f);
            ushort_t bb = f2bf(v);
            Ab[(wave * 16 + quad * 4 + i) * ASTR + col] = bb;
            if (orow0 + i < NN) {
                float vr2 = bf2f(bb);
                ls += vr2;
                lq = fmaf(vr2, vr2, lq);
            }
        }
        ls += __shfl_xor(ls, 16, 64);
        ls += __shfl_xor(ls, 32, 64);
        lq += __shfl_xor(lq, 16, 64);
        lq += __shfl_xor(lq, 32, 64);
        if (quad == 0) {
            atomicAdd(&sstat[col], ls);
            atomicAdd(&sstat[128 + col], lq);
        }
    }

    // Full-line stores: per iteration, each quad stores one FULL 256-B row.
    // perm comes from the hoisted registers via shfl (no reload).
    #pragma unroll
    for (int it = 0; it < 4; ++it) {
        int pr = __shfl(prm, it * 4 + quad, 64);
        int ridx = rowbase + it * 4 + quad;
        if (ridx < NN) {
            short8 v = *(const short8*)&Ab[(wave * 16 + it * 4 + quad) * ASTR + l15 * 8];
            *(short8*)(hout + (size_t)pr * 128 + l15 * 8) = v;
        }
    }

    __syncthreads();   // all waves' sstat atomics complete
    partials[(size_t)blockIdx.x * 256 + t] = sstat[t];   // coalesced 1 KB store
}

// ---------------- Partial-stats reduction: 1563 x 256 -> 256 (64 blocks) -----------

__global__ __launch_bounds__(256) void k_red(const float* __restrict__ partials,
                                             float* __restrict__ stats) {
    int t = threadIdx.x;
    float s = 0.f;
    for (int r = blockIdx.x; r < NB; r += 64) s += partials[(size_t)r * 256 + t];
    atomicAdd(&stats[t], s);
}

// ---------------- Pooling, phase 1 (+ folded layer-5 stats reduction) ---------

__device__ __forceinline__ int lowerb(const int* __restrict__ b, int n, int key) {
    int lo = 0, hi = n;
    while (lo < hi) {
        int mid = (lo + hi) >> 1;
        if (b[mid] < key) lo = mid + 1;
        else hi = mid;
    }
    return lo;
}

__global__ __launch_bounds__(256) void k_pool1(
    const ushort_t* __restrict__ h, const int* __restrict__ batch,
    float* __restrict__ ppart,
    const float* __restrict__ red_src, float* __restrict__ stats5) {
    int t = threadIdx.x;
    // folded k_red for layer 5 (consumed by k_tail, next dispatch -- stream order)
    if (blockIdx.x < 64) {
        float s = 0.f;
        for (int r = blockIdx.x; r < NB; r += 64)
            s += red_src[(size_t)r * 256 + t];
        atomicAdd(&stats5[t], s);
    }
    int g = blockIdx.x >> 4;
    int sl = blockIdx.x & (PSL - 1);
    int lo = lowerb(batch, NN, g);
    int hi = lowerb(batch, NN, g + 1);
    int cnt = hi - lo;
    int a = lo + (int)(((long long)cnt * sl) >> 4);
    int b = lo + (int)(((long long)cnt * (sl + 1)) >> 4);
    int wave = t >> 6, lane = t & 63;
    const ushort2* h2 = (const ushort2*)h;
    float ax = 0.f, ay = 0.f;
    for (int n = a + wave; n < b; n += 4) {
        ushort2 v = h2[(size_t)n * 64 + lane];
        ax += bf2f(v.x);
        ay += bf2f(v.y);
    }
    __shared__ float2 red[4][64];
    red[wave][lane] = make_float2(ax, ay);
    __syncthreads();
    if (wave == 0) {
        float sx = 0.f, sy = 0.f;
        for (int w = 0; w < 4; ++w) {
            sx += red[w][lane].x;
            sy += red[w][lane].y;
        }
        ((float2*)ppart)[(size_t)blockIdx.x * 64 + lane] = make_float2(sx, sy);
    }
}

// ---------------- Tail: combine slices + deferred BN affine + MLP head + log_softmax

__global__ __launch_bounds__(64) void k_tail(
    const float* __restrict__ ppart, const int* __restrict__ batch,
    const float* __restrict__ stats, const float* __restrict__ bng, const float* __restrict__ bnb,
    const float* __restrict__ w1, const float* __restrict__ b1,
    const float* __restrict__ w2, const float* __restrict__ b2,
    float* __restrict__ out) {
    __shared__ float p[128];
    int g = blockIdx.x;
    int lane = threadIdx.x;
    float sx = 0.f, sy = 0.f;
    #pragma unroll
    for (int s = 0; s < PSL; ++s) {
        float2 v = ((const float2*)ppart)[(size_t)(g * PSL + s) * 64 + lane];
        sx += v.x;
        sy += v.y;
    }
    int cnt = lowerb(batch, NN, g + 1) - lowerb(batch, NN, g);
    int c0 = lane * 2;
    const float inv_n = 1.0f / (float)NN;
    float m0 = stats[c0] * inv_n, m1 = stats[c0 + 1] * inv_n;
    float var0 = fmaf(-m0, m0, stats[HD + c0] * inv_n);
    float var1 = fmaf(-m1, m1, stats[HD + c0 + 1] * inv_n);
    float sc0 = bng[c0] * rsqrtf(var0 + 1e-5f);
    float sc1 = bng[c0 + 1] * rsqrtf(var1 + 1e-5f);
    float sh0 = bnb[c0] - m0 * sc0;
    float sh1 = bnb[c0 + 1] - m1 * sc1;
    float denom = fmaxf((float)cnt, 1.f);
    p[c0] = (sc0 * sx + (float)cnt * sh0) / denom;
    p[c0 + 1] = (sc1 * sy + (float)cnt * sh1) / denom;
    __syncthreads();

    float hid = b1[lane];
    #pragma unroll 8
    for (int k = 0; k < 128; ++k) hid = fmaf(p[k], w1[k * 64 + lane], hid);
    float o[4];
    #pragma unroll
    for (int c = 0; c < 4; ++c) {
        float v = hid * w2[lane * 4 + c];
        #pragma unroll
        for (int off = 1; off < 64; off <<= 1) v += __shfl_xor(v, off, 64);
        o[c] = v + b2[c];
    }
    if (lane == 0) {
        float mx = fmaxf(fmaxf(o[0], o[1]), fmaxf(o[2], o[3]));
        float se = expf(o[0] - mx) + expf(o[1] - mx) + expf(o[2] - mx) + expf(o[3] - mx);
        float ls = mx + logf(se);
        #pragma unroll
        for (int c = 0; c < 4; ++c) out[g * 4 + c] = o[c] - ls;
    }
}

extern "C" void kernel_launch(void* const* d_in, const int* in_sizes, int n_in,
                              void* d_out, int out_size, void* d_ws, size_t ws_size,
                              hipStream_t stream) {
    const float* x = (const float*)d_in[0];
    const int* ei = (const int*)d_in[1];
    const int* batch = (const int*)d_in[2];
    const float* conv_w = (const float*)d_in[3];
    const float* conv_b = (const float*)d_in[4];
    const float* bn_g = (const float*)d_in[5];
    const float* bn_b = (const float*)d_in[6];
    const float* l1w = (const float*)d_in[7];
    const float* l1b = (const float*)d_in[8];
    const float* l2w = (const float*)d_in[9];
    const float* l2b = (const float*)d_in[10];
    float* out = (float*)d_out;
    (void)in_sizes; (void)n_in; (void)out_size; (void)ws_size;

    char* ws = (char*)d_ws;
    int* counts = (int*)(ws + 0);               // 400000 B
    int* cursor = (int*)(ws + 400000);          // 400000 B
    int* perm = (int*)(ws + 400000);            // reuse after k_filldh
    float* stats = (float*)(ws + 800000);       // 6*256 floats -> 806144
    int* dcount = (int*)(ws + 806144);          // 256 B
    int* dcursor = (int*)(ws + 806400);         // 256 B -> 806656
    const size_t zero_bytes = 806656;           // counts+cursor+stats+dcount+dcursor
    int* rowptr = (int*)(ws + 806656);          // 100001 ints -> 1206660
    int* bsums = (int*)(ws + 1206664);          // 391 ints -> 1208228
    int* colsrc = (int*)(ws + 1208256);         // 600000 ints + 1 KiB pad -> 3609280
    float* ppart = (float*)(ws + 3609280);      // 1024*128 floats -> 4133568
    float* partials = (float*)(ws + 4133568);   // 1563*256 floats -> 5734080
    ushort_t* xb = (ushort_t*)(ws + 5734144);   // 25600256 B -> 31334400
    ushort_t* hb0 = (ushort_t*)(ws + 31334400); // 25600256 B -> 56934656
    ushort_t* hb1 = (ushort_t*)(ws + 56934656); // 25600256 B -> 82534912
    ushort_t* wtbuf = (ushort_t*)(ws + 82534912); // 196608 B -> 82731520

    hipMemsetAsync(ws, 0, zero_bytes, stream);

    // cast + wcast + zero rows + edge histogram in one grid
    k_prep<<<CASTB + NL + EBL, 256, 0, stream>>>(x, xb, conv_w, wtbuf, hb0, hb1, ei, counts);

    int nb1 = (NN + 255) / 256;   // 391
    k_scan1<<<nb1, 256, 0, stream>>>(counts, bsums);
    k_scan3m<<<nb1, 256, 0, stream>>>(counts, bsums, rowptr);
    k_filldh<<<EBL + nb1, 256, 0, stream>>>(ei, rowptr, cursor, colsrc, dcount, EBL);
    k_dfill2<<<nb1, 256, 0, stream>>>(rowptr, dcount, dcursor, perm);

    // ping-pong h buffers: gconv reads hin, writes hout (never in place)
    ushort_t* hb[2] = {hb0, hb1};
    for (int L = 0; L < NL; ++L) {
        const ushort_t* hin = (L == 0) ? xb : hb[(L + 1) & 1];
        ushort_t* hout = hb[L & 1];
        const float* lstats = (L == 0) ? nullptr : (stats + (L - 1) * 256);
        const float* lg = (L == 0) ? nullptr : (bn_g + (L - 1) * 128);
        const float* lb = (L == 0) ? nullptr : (bn_b + (L - 1) * 128);
        k_gconv<<<NB, 256, 0, stream>>>(hin, perm, rowptr, colsrc, lstats, lg, lb,
                                        wtbuf + L * 16384, conv_b + L * 128,
                                        hout, partials);
        if (L < NL - 1)
            k_red<<<64, 256, 0, stream>>>(partials, stats + L * 256);
    }
    // final h is hb[5&1] = hb1; layer-5 stats reduction folded into pool1
    k_pool1<<<NG * PSL, 256, 0, stream>>>(hb1, batch, ppart, partials, stats + 5 * 256);
    k_tail<<<NG, 64, 0, stream>>>(ppart, batch, stats + 5 * 256, bn_g + 5 * 128, bn_b + 5 * 128,
                                  l1w, l1b, l2w, l2b, out);
}